// Round 1
// baseline (29.023 us; speedup 1.0000x reference)
//
#include <hip/hip_runtime.h>

// RollingSignatureFeatures: B=64, S=2048, D=15, W=5, d=D+1=16, out=(B,S,272) fp32.
// level1[j]    = aug[s][j] - aug[max(s-4,0)][j]
// level2[i][j] = sum_{w=0..3} (aug[c(s+w-3)][i] - aug[c(s+w-4)][i]) * aug[c(s+w-4)][j]
// aug = [s/(S-1), features[s]], c() clamps at 0.

namespace {
constexpr int kB = 64;
constexpr int kS = 2048;
constexpr int kD = 15;
constexpr int kDD = 16;              // D + 1
constexpr int kW = 5;
constexpr int kTS = 64;              // output positions per block
constexpr int kRows = kTS + kW - 1;  // 68 staged aug rows
constexpr int kStride = 20;          // LDS row stride (floats): 80B -> 16B-aligned float4, 2-way max conflict
constexpr int kOut = kDD + kDD * kDD;  // 272 floats per position
}

__global__ __launch_bounds__(256, 4) void rollsig_kernel(const float* __restrict__ feat,
                                                         float* __restrict__ out) {
    const int tilesPerB = kS / kTS;  // 32
    const int b = blockIdx.x / tilesPerB;
    const int s0 = (blockIdx.x % tilesPerB) * kTS;

    __shared__ float lds[kRows * kStride];

    const int tid = threadIdx.x;
    const float* fb = feat + (size_t)b * kS * kD;

    // Stage features into aug channels 1..15 (coalesced: consecutive f -> consecutive gmem)
    for (int f = tid; f < kRows * kD; f += 256) {
        int r = f / kD;
        int c = f - r * kD;
        int s = s0 + r - (kW - 1);
        int sc = s < 0 ? 0 : s;
        lds[r * kStride + 1 + c] = fb[(size_t)sc * kD + c];
    }
    // Time channel (linspace(0,1,S)[s] = s * (1/(S-1)))
    for (int r = tid; r < kRows; r += 256) {
        int s = s0 + r - (kW - 1);
        int sc = s < 0 ? 0 : s;
        lds[r * kStride] = (float)sc * (1.0f / (float)(kS - 1));
    }
    __syncthreads();

    const int p = tid >> 2;  // position within tile, 0..63
    const int q = tid & 3;   // j-quad owner, 0..3
    const int s = s0 + p;

    // Full window rows in registers (static indices only; runtime p lives in the LDS address)
    float win[kW][kDD];
#pragma unroll
    for (int w = 0; w < kW; ++w) {
#pragma unroll
        for (int i4 = 0; i4 < 4; ++i4) {
            float4 v = *(const float4*)&lds[(p + w) * kStride + i4 * 4];
            win[w][i4 * 4 + 0] = v.x;
            win[w][i4 * 4 + 1] = v.y;
            win[w][i4 * 4 + 2] = v.z;
            win[w][i4 * 4 + 3] = v.w;
        }
    }
    // This thread's j-quad of each window row (runtime q -> LDS address, not register index)
    float4 l4[kW];
#pragma unroll
    for (int w = 0; w < kW; ++w) {
        l4[w] = *(const float4*)&lds[(p + w) * kStride + q * 4];
    }

    float* ob = out + ((size_t)b * kS + s) * kOut;

    // level1: j-quad q. Lanes (p, q=0..3) write 64 contiguous bytes.
    float4 l1;
    l1.x = l4[4].x - l4[0].x;
    l1.y = l4[4].y - l4[0].y;
    l1.z = l4[4].z - l4[0].z;
    l1.w = l4[4].w - l4[0].w;
    *(float4*)(ob + q * 4) = l1;

    // level2 rows i = 0..15, columns q*4..q*4+3
#pragma unroll
    for (int i = 0; i < kDD; ++i) {
        float4 acc = make_float4(0.f, 0.f, 0.f, 0.f);
#pragma unroll
        for (int w = 0; w < 4; ++w) {
            float inc = win[w + 1][i] - win[w][i];
            acc.x = fmaf(inc, l4[w].x, acc.x);
            acc.y = fmaf(inc, l4[w].y, acc.y);
            acc.z = fmaf(inc, l4[w].z, acc.z);
            acc.w = fmaf(inc, l4[w].w, acc.w);
        }
        *(float4*)(ob + kDD + i * kDD + q * 4) = acc;
    }
}

extern "C" void kernel_launch(void* const* d_in, const int* in_sizes, int n_in,
                              void* d_out, int out_size, void* d_ws, size_t ws_size,
                              hipStream_t stream) {
    const float* feat = (const float*)d_in[0];
    float* out = (float*)d_out;
    dim3 grid(kB * (kS / kTS));  // 2048 blocks
    rollsig_kernel<<<grid, 256, 0, stream>>>(feat, out);
}